// Round 15
// baseline (261.762 us; speedup 1.0000x reference)
//
#include <hip/hip_runtime.h>
#include <math.h>

#define LN      2048
#define LOG2L   11
#define BB      16
#define HE      512            // H*E channels
#define KTOP    7              // int(log(2048)) = 7
#define TWO_PI  6.283185307179586f
#define RC      0.70710678118654752f

// XOR swizzle on element index for LDS FFT buffers.
#define SIG(e)  ((e) ^ (((e) >> 5) & 31))

struct c32 { float x, y; };
__device__ __forceinline__ c32 cmul(c32 a, c32 b) {
    return { a.x * b.x - a.y * b.y, a.x * b.y + a.y * b.x };
}
__device__ __forceinline__ c32 cadd(c32 a, c32 b) { return { a.x + b.x, a.y + b.y }; }
__device__ __forceinline__ c32 csub(c32 a, c32 b) { return { a.x - b.x, a.y - b.y }; }

__device__ __forceinline__ void dft4(c32 a, c32 b, c32 c, c32 d,
                                     c32& y0, c32& y1, c32& y2, c32& y3) {
    c32 t0 = cadd(a, c), t1 = csub(a, c);
    c32 t2 = cadd(b, d);
    c32 t3 = { b.y - d.y, d.x - b.x };          // -i*(b-d)
    y0 = cadd(t0, t2);
    y1 = cadd(t1, t3);
    y2 = csub(t0, t2);
    y3 = csub(t1, t3);
}

__device__ __forceinline__ void dft8(const c32* x, c32* y) {
    c32 e0, e1, e2, e3, o0, o1, o2, o3;
    dft4(x[0], x[2], x[4], x[6], e0, e1, e2, e3);
    dft4(x[1], x[3], x[5], x[7], o0, o1, o2, o3);
    c32 p1 = { RC * (o1.x + o1.y), RC * (o1.y - o1.x) };
    c32 p2 = { o2.y, -o2.x };
    c32 p3 = { RC * (o3.y - o3.x), -RC * (o3.x + o3.y) };
    y[0] = cadd(e0, o0); y[4] = csub(e0, o0);
    y[1] = cadd(e1, p1); y[5] = csub(e1, p1);
    y[2] = cadd(e2, p2); y[6] = csub(e2, p2);
    y[3] = cadd(e3, p3); y[7] = csub(e3, p3);
}

// Twiddle set for one stage: W[k-1] = W_2048^{pm*k}, k=1..7 (tree, depth<=2).
__device__ __forceinline__ void mk_tw(int pm, c32* W) {
    float sn, cs;
    __sincosf(-(TWO_PI / (float)LN) * (float)pm, &sn, &cs);
    const c32 w1 = { cs, sn };
    const c32 w2 = cmul(w1, w1);
    const c32 w3 = cmul(w1, w2);
    const c32 w4 = cmul(w2, w2);
    W[0] = w1; W[1] = w2; W[2] = w3; W[3] = w4;
    W[4] = cmul(w1, w4); W[5] = cmul(w2, w4); W[6] = cmul(w3, w4);
}

// Whole-WG Stockham DIF radix-8 stage; twiddles from a small LDS table
// (8-lane broadcast reads) — keeps persistent VGPR state minimal.
template<int LOG2M>
__device__ __forceinline__ void r8_ld_tab(float2* Z, int tid,
                                          const float2* __restrict__ tab) {
    c32 v[8];
    #pragma unroll
    for (int r = 0; r < 8; ++r) {
        float2 z = Z[SIG(tid + (r << 8))];
        v[r] = { z.x, z.y };
    }
    c32 y[8];
    dft8(v, y);
    #pragma unroll
    for (int kk = 1; kk < 8; ++kk) {
        const float2 w = tab[kk - 1];
        y[kk] = cmul(y[kk], { w.x, w.y });
    }
    __syncthreads();
    const int q_ = tid & ((1 << LOG2M) - 1);
    const int ob = q_ + ((tid - q_) << 3);       // q + 8*m*p
    #pragma unroll
    for (int kk = 0; kk < 8; ++kk)
        Z[SIG(ob + (kk << LOG2M))] = make_float2(y[kk].x, y[kk].y);
    __syncthreads();
}

// Final radix-4 stage, m=512 (twiddle-free), 512 butterflies / 256 threads.
__device__ __forceinline__ void r4_final_wg(float2* Z, int tid) {
    c32 v[2][4];
    #pragma unroll
    for (int u = 0; u < 2; ++u) {
        const int j = tid + (u << 8);
        #pragma unroll
        for (int r = 0; r < 4; ++r) {
            float2 z = Z[SIG(j + (r << 9))];
            v[u][r] = { z.x, z.y };
        }
    }
    __syncthreads();
    #pragma unroll
    for (int u = 0; u < 2; ++u) {
        const int j = tid + (u << 8);
        c32 y0, y1, y2, y3;
        dft4(v[u][0], v[u][1], v[u][2], v[u][3], y0, y1, y2, y3);
        Z[SIG(j)]        = make_float2(y0.x, y0.y);
        Z[SIG(j + 512)]  = make_float2(y1.x, y1.y);
        Z[SIG(j + 1024)] = make_float2(y2.x, y2.y);
        Z[SIG(j + 1536)] = make_float2(y3.x, y3.y);
    }
    __syncthreads();
}

// ---------------------------------------------------------------------------
// Kernel T v3: coalesced transpose, float4 both global sides, writes PACKED
// z = (q,k) float2 into [b][c][l] complex array split across zlo (b<8, ws)
// and zhi (b>=8, d_out).
// ---------------------------------------------------------------------------
__global__ __launch_bounds__(256) void transpose_pack_kernel(
    const float* __restrict__ q, const float* __restrict__ k,
    float* __restrict__ zlo, float* __restrict__ zhi) {
    __shared__ float2 tile[64][65];
    const int tid = threadIdx.x;
    const int bid = blockIdx.x;
    const int b  = bid >> 8;
    const int lt = (bid >> 3) & 31;
    const int ct = bid & 7;
    const int l0 = lt << 6, c0 = ct << 6;
    const int g16 = tid >> 4;               // 0..15
    const int m16 = (tid & 15) << 2;        // 0,4,..,60
    #pragma unroll
    for (int ii = 0; ii < 4; ++ii) {
        const int r = g16 + (ii << 4);      // l offset 0..63
        const size_t src = ((size_t)(b * LN + l0 + r)) * HE + c0 + m16;
        const float4 qv = *(const float4*)(q + src);
        const float4 kv = *(const float4*)(k + src);
        tile[r][m16 + 0] = make_float2(qv.x, kv.x);
        tile[r][m16 + 1] = make_float2(qv.y, kv.y);
        tile[r][m16 + 2] = make_float2(qv.z, kv.z);
        tile[r][m16 + 3] = make_float2(qv.w, kv.w);
    }
    __syncthreads();
    float* zb = (b < 8) ? zlo : zhi;
    const int bb = b & 7;
    #pragma unroll
    for (int ii = 0; ii < 4; ++ii) {
        const int rc = g16 + (ii << 4);     // c offset 0..63
        const float2 t0 = tile[m16 + 0][rc];
        const float2 t1 = tile[m16 + 1][rc];
        const float2 t2 = tile[m16 + 2][rc];
        const float2 t3 = tile[m16 + 3][rc];
        float* dst = zb + (((size_t)(bb * HE + c0 + rc)) * LN + l0 + m16) * 2;
        *(float4*)(dst)     = make_float4(t0.x, t0.y, t1.x, t1.y);
        *(float4*)(dst + 4) = make_float4(t2.x, t2.y, t3.x, t3.y);
    }
}

// ---------------------------------------------------------------------------
// Kernel A (slim): r13 structure with minimal persistent registers —
// TW0 transient per channel, TW1/TW2 in 2 KB LDS tables (broadcast reads),
// __launch_bounds__(256,7) -> VGPR cap 73, 7 waves/SIMD.
// ---------------------------------------------------------------------------
__global__ __launch_bounds__(256, 7) void fft_slim_kernel(
    const float* __restrict__ zlo, const float* __restrict__ zhi,
    float* __restrict__ spec /* [BB][LN][2], only f<=1024 written */) {
    __shared__ float2 Z[LN];                     // 16 KB
    __shared__ float2 tw1[32][7];                // 1.75 KB
    __shared__ float2 tw2[4][7];                 // 224 B
    const int tid = threadIdx.x;
    const int wg  = blockIdx.x;                  // 2048
    const int b   = wg >> 7;                     // input-L2-locality mapping
    const int c0  = (wg & 127) << 2;
    const float2* zbase = (const float2*)((b < 8) ? zlo : zhi);
    const int bb  = b & 7;

    // one-time twiddle tables (first read is 2 barriers later - safe)
    if (tid < 32) {
        c32 W[7];
        mk_tw(tid << 3, W);
        #pragma unroll
        for (int j = 0; j < 7; ++j) tw1[tid][j] = make_float2(W[j].x, W[j].y);
    }
    if (tid < 4) {
        c32 W[7];
        mk_tw(tid << 6, W);
        #pragma unroll
        for (int j = 0; j < 7; ++j) tw2[tid][j] = make_float2(W[j].x, W[j].y);
    }

    float accx[4], accy[4];
    #pragma unroll
    for (int i = 0; i < 4; ++i) { accx[i] = 0.f; accy[i] = 0.f; }
    float a1024 = 0.f;

    #pragma unroll 1
    for (int ch = 0; ch < 4; ++ch) {
        const float2* zc = zbase + (((size_t)(bb * HE + c0 + ch)) << LOG2L);
        // stage 0 straight from global (packed float2, coalesced)
        c32 v[8];
        #pragma unroll
        for (int r = 0; r < 8; ++r) {
            const float2 t = zc[tid + (r << 8)];
            v[r] = { t.x, t.y };
        }
        c32 y[8];
        dft8(v, y);
        {   // TW0 transient (registers die immediately)
            c32 W[7];
            mk_tw(tid, W);
            #pragma unroll
            for (int kk = 1; kk < 8; ++kk) y[kk] = cmul(y[kk], W[kk - 1]);
        }
        __syncthreads();                         // Z free (prev unpack done)
        #pragma unroll
        for (int kk = 0; kk < 8; ++kk)           // ob = 8*tid, contiguous
            Z[SIG((tid << 3) + kk)] = make_float2(y[kk].x, y[kk].y);
        __syncthreads();

        r8_ld_tab<3>(Z, tid, &tw1[tid >> 3][0]);
        r8_ld_tab<6>(Z, tid, &tw2[tid >> 6][0]);
        r4_final_wg(Z, tid);

        // Hermitian-half unpack: S = Q*conj(K), f in [0,1024)
        #pragma unroll
        for (int i = 0; i < 4; ++i) {
            const int f = tid + (i << 8);
            const int g = (LN - f) & (LN - 1);
            const float2 zf = Z[SIG(f)];
            const float2 zm = Z[SIG(g)];
            const float Qr = 0.5f * (zf.x + zm.x);
            const float Qi = 0.5f * (zf.y - zm.y);
            const float Kr = 0.5f * (zf.y + zm.y);
            const float Ki = -0.5f * (zf.x - zm.x);
            accx[i] += Qr * Kr + Qi * Ki;
            accy[i] += Qi * Kr - Qr * Ki;
        }
        if (tid == 0) {                          // f = 1024: S real
            const float2 zf = Z[SIG(1024)];
            a1024 += zf.x * zf.y;
        }
    }
    #pragma unroll
    for (int i = 0; i < 4; ++i) {
        const int f = tid + (i << 8);
        atomicAdd(&spec[((size_t)b * LN + f) * 2 + 0], accx[i]);
        atomicAdd(&spec[((size_t)b * LN + f) * 2 + 1], accy[i]);
    }
    if (tid == 0)
        atomicAdd(&spec[((size_t)b * LN + 1024) * 2 + 0], a1024);
}

// ---------------------------------------------------------------------------
// Fallback (raw layout, round-3 path; flush gated to f<=1024) — only if ws
// is too small for the packed staging buffers.
// ---------------------------------------------------------------------------
template<int LOG2M>
__device__ __forceinline__ void r8_stage(float2* Z, int lane) {
    c32 v[32];
    #pragma unroll
    for (int u = 0; u < 4; ++u) {
        const int j = lane + (u << 6);
        #pragma unroll
        for (int r = 0; r < 8; ++r) {
            float2 z = Z[SIG(j + (r << 8))];
            v[(u << 3) + r] = { z.x, z.y };
        }
    }
    c32 y[32];
    #pragma unroll
    for (int u = 0; u < 4; ++u) {
        const int j  = lane + (u << 6);
        const int pm = j & ~((1 << LOG2M) - 1);
        dft8(&v[u << 3], &y[u << 3]);
        float sn, cs;
        __sincosf(-(TWO_PI / (float)LN) * (float)pm, &sn, &cs);
        c32 base = { cs, sn };
        c32 t = base;
        #pragma unroll
        for (int kk = 1; kk < 8; ++kk) {
            y[(u << 3) + kk] = cmul(y[(u << 3) + kk], t);
            if (kk < 7) t = cmul(t, base);
        }
    }
    __syncthreads();
    #pragma unroll
    for (int u = 0; u < 4; ++u) {
        const int j  = lane + (u << 6);
        const int q_ = j & ((1 << LOG2M) - 1);
        const int ob = q_ + ((j - q_) << 3);
        #pragma unroll
        for (int kk = 0; kk < 8; ++kk) {
            c32 yy = y[(u << 3) + kk];
            Z[SIG(ob + (kk << LOG2M))] = make_float2(yy.x, yy.y);
        }
    }
    __syncthreads();
}

__device__ __forceinline__ void r4_final(float2* Z, int lane) {
    c32 v[32];
    #pragma unroll
    for (int u = 0; u < 8; ++u) {
        const int j = lane + (u << 6);
        #pragma unroll
        for (int r = 0; r < 4; ++r) {
            float2 z = Z[SIG(j + (r << 9))];
            v[(u << 2) + r] = { z.x, z.y };
        }
    }
    __syncthreads();
    #pragma unroll
    for (int u = 0; u < 8; ++u) {
        const int j = lane + (u << 6);
        c32 y0, y1, y2, y3;
        dft4(v[u << 2], v[(u << 2) + 1], v[(u << 2) + 2], v[(u << 2) + 3],
             y0, y1, y2, y3);
        Z[SIG(j)]        = make_float2(y0.x, y0.y);
        Z[SIG(j + 512)]  = make_float2(y1.x, y1.y);
        Z[SIG(j + 1024)] = make_float2(y2.x, y2.y);
        Z[SIG(j + 1536)] = make_float2(y3.x, y3.y);
    }
    __syncthreads();
}

__global__ __launch_bounds__(256) void fft_fused_kernel(
    const float* __restrict__ qg, const float* __restrict__ kg,
    float* __restrict__ spec) {
    __shared__ float2 zb[4][LN];
    const int t    = threadIdx.x;
    const int bid  = blockIdx.x;
    const int wgid = ((bid & 7) << 8) | (bid >> 3);
    const int b    = wgid >> 7;
    const int c0   = (wgid & 127) << 2;
    #pragma unroll
    for (int i = 0; i < 8; ++i) {
        const int l = t + (i << 8);
        const size_t base = (size_t)(b * LN + l) * HE + c0;
        const float4 qv = *(const float4*)(qg + base);
        const float4 kv = *(const float4*)(kg + base);
        const int sl = SIG(l);
        zb[0][sl] = make_float2(qv.x, kv.x);
        zb[1][sl] = make_float2(qv.y, kv.y);
        zb[2][sl] = make_float2(qv.z, kv.z);
        zb[3][sl] = make_float2(qv.w, kv.w);
    }
    __syncthreads();
    const int w    = t >> 6;
    const int lane = t & 63;
    float2* Z = zb[w];
    r8_stage<0>(Z, lane);
    r8_stage<3>(Z, lane);
    r8_stage<6>(Z, lane);
    r4_final(Z, lane);
    float sx[32], sy[32];
    #pragma unroll
    for (int i = 0; i < 32; ++i) {
        const int f = lane + (i << 6);
        const float2 zf = Z[SIG(f)];
        const float2 zm = Z[SIG((LN - f) & (LN - 1))];
        const float Qr = 0.5f * (zf.x + zm.x);
        const float Qi = 0.5f * (zf.y - zm.y);
        const float Kr = 0.5f * (zf.y + zm.y);
        const float Ki = -0.5f * (zf.x - zm.x);
        sx[i] = Qr * Kr + Qi * Ki;
        sy[i] = Qi * Kr - Qr * Ki;
    }
    __syncthreads();
    #pragma unroll
    for (int i = 0; i < 32; ++i) {
        const int f = lane + (i << 6);
        Z[SIG(f)] = make_float2(sx[i], sy[i]);
    }
    __syncthreads();
    #pragma unroll
    for (int i = 0; i < 8; ++i) {
        const int f  = t + (i << 8);
        if (f <= 1024) {
            const int sf = SIG(f);
            const float rx = zb[0][sf].x + zb[1][sf].x + zb[2][sf].x + zb[3][sf].x;
            const float ry = zb[0][sf].y + zb[1][sf].y + zb[2][sf].y + zb[3][sf].y;
            atomicAdd(&spec[((size_t)b * LN + f) * 2 + 0], rx);
            atomicAdd(&spec[((size_t)b * LN + f) * 2 + 1], ry);
        }
    }
}

// ---------------------------------------------------------------------------
// Kernel B: per-b inverse transform -> mean corr, top-7 + softmax.
// Spectrum stored Hermitian-half: reflect for f > 1024.
// ---------------------------------------------------------------------------
__device__ __forceinline__ unsigned bitrev11(unsigned x) {
    return __brev(x) >> (32 - LOG2L);
}

__global__ __launch_bounds__(256) void icorr_topk_kernel(
    const float* __restrict__ spec, float* __restrict__ wts, int* __restrict__ tao) {
    __shared__ float2 zbuf[LN];
    __shared__ float2 tw[LN / 2];
    __shared__ float  cr[LN];
    __shared__ float  rv[256];
    __shared__ int    ri[256];
    __shared__ float  topv[KTOP];
    __shared__ int    topi[KTOP];
    const int tid = threadIdx.x;
    const int b   = blockIdx.x;
    for (int p = tid; p < LN / 2; p += 256) {
        float s, c;
        sincosf(-TWO_PI * (float)p / (float)LN, &s, &c);
        tw[p] = make_float2(c, s);
    }
    for (int f = tid; f < LN; f += 256) {
        const int  fs  = (f <= 1024) ? f : (LN - f);
        const float sg = (f <= 1024) ? -1.f : 1.f;   // zbuf = conj(S[f])
        float sr = spec[((size_t)b * LN + fs) * 2 + 0];
        float si = spec[((size_t)b * LN + fs) * 2 + 1];
        zbuf[bitrev11((unsigned)f)] = make_float2(sr, sg * si);
    }
    __syncthreads();
    for (int s = 0; s < LOG2L; ++s) {
        const int half = 1 << s;
        for (int j = tid; j < LN / 2; j += 256) {
            const int grp = j >> s;
            const int pos = j & (half - 1);
            const int i0  = (grp << (s + 1)) + pos;
            const int i1  = i0 + half;
            const float2 w = tw[pos << (LOG2L - 1 - s)];
            float2 a  = zbuf[i0];
            float2 bv = zbuf[i1];
            float tr = w.x * bv.x - w.y * bv.y;
            float ti = w.x * bv.y + w.y * bv.x;
            zbuf[i0] = make_float2(a.x + tr, a.y + ti);
            zbuf[i1] = make_float2(a.x - tr, a.y - ti);
        }
        __syncthreads();
    }
    const float scale = 1.0f / ((float)LN * (float)HE);
    for (int t = tid; t < LN; t += 256) cr[t] = zbuf[t].x * scale;
    __syncthreads();
    for (int it = 0; it < KTOP; ++it) {
        float mv = -INFINITY;
        int   mi = 0;
        for (int t = tid; t < LN; t += 256) {
            float v = cr[t];
            if (v > mv) { mv = v; mi = t; }
        }
        rv[tid] = mv; ri[tid] = mi;
        __syncthreads();
        for (int off = 128; off > 0; off >>= 1) {
            if (tid < off) {
                float ov = rv[tid + off]; int oi = ri[tid + off];
                if (ov > rv[tid] || (ov == rv[tid] && oi < ri[tid])) {
                    rv[tid] = ov; ri[tid] = oi;
                }
            }
            __syncthreads();
        }
        if (tid == 0) {
            topv[it] = rv[0];
            topi[it] = ri[0];
            cr[ri[0]] = -INFINITY;
        }
        __syncthreads();
    }
    if (tid == 0) {
        float m = topv[0];
        float s = 0.f;
        float ex[KTOP];
        for (int j = 0; j < KTOP; ++j) { ex[j] = __expf(topv[j] - m); s += ex[j]; }
        float inv = 1.0f / s;
        for (int j = 0; j < KTOP; ++j) {
            wts[b * 8 + j] = ex[j] * inv;
            tao[b * 8 + j] = topi[j];
        }
    }
}

// ---------------------------------------------------------------------------
// Kernel C: out[b,l,:,:] = sum_j w[b,j] * V[b,(l+tao_j)%L,:,:]
// ---------------------------------------------------------------------------
__global__ __launch_bounds__(256) void gather_kernel(
    const float* __restrict__ v, const float* __restrict__ wts,
    const int* __restrict__ tao, float* __restrict__ out) {
    __shared__ float lw[KTOP];
    __shared__ int   lt[KTOP];
    const int tid = threadIdx.x;
    const int bid = blockIdx.x;
    const int wg  = ((bid & 7) << 11) | (bid >> 3);
    const long long idx = (long long)wg * 256 + tid;
    const int c4 = (int)(idx & 127);
    const int l  = (int)((idx >> 7) & (LN - 1));
    const int b  = (int)(idx >> 18);
    if (tid < KTOP) {
        lw[tid] = wts[b * 8 + tid];
        lt[tid] = tao[b * 8 + tid];
    }
    __syncthreads();
    const float4* v4 = (const float4*)v;
    float4 a = make_float4(0.f, 0.f, 0.f, 0.f);
    #pragma unroll
    for (int j = 0; j < KTOP; ++j) {
        int ls = (l + lt[j]) & (LN - 1);
        float4 x = v4[((size_t)b * LN + ls) * 128 + c4];
        float w = lw[j];
        a.x += w * x.x; a.y += w * x.y; a.z += w * x.z; a.w += w * x.w;
    }
    ((float4*)out)[idx] = a;
}

// ---------------------------------------------------------------------------
extern "C" void kernel_launch(void* const* d_in, const int* in_sizes, int n_in,
                              void* d_out, int out_size, void* d_ws, size_t ws_size,
                              hipStream_t stream) {
    const float* q = (const float*)d_in[0];
    const float* k = (const float*)d_in[1];
    const float* v = (const float*)d_in[2];
    float* out = (float*)d_out;

    const size_t nT   = (size_t)BB * HE * LN;          // 16.7M floats = 64 MB
    const size_t need = nT * 4 + (size_t)BB * LN * 2 * 4 + (size_t)BB * 8 * 8;

    if (ws_size >= need) {
        float* zlo  = (float*)d_ws;                 // b<8 packed z: 64 MB
        float* spec = zlo + nT;
        float* wts  = spec + (size_t)BB * LN * 2;
        int*   tao  = (int*)(wts + BB * 8);
        float* zhi  = out;                          // b>=8 packed z: d_out

        hipMemsetAsync(spec, 0, (size_t)BB * LN * 2 * sizeof(float), stream);
        transpose_pack_kernel<<<BB * 32 * 8, 256, 0, stream>>>(q, k, zlo, zhi);
        fft_slim_kernel<<<BB * (HE / 4), 256, 0, stream>>>(zlo, zhi, spec);
        icorr_topk_kernel<<<BB, 256, 0, stream>>>(spec, wts, tao);
        const int n4 = BB * LN * HE / 4;
        gather_kernel<<<n4 / 256, 256, 0, stream>>>(v, wts, tao, out);
    } else {
        float* spec = (float*)d_ws;
        float* wts  = spec + (size_t)BB * LN * 2;
        int*   tao  = (int*)(wts + BB * 8);
        hipMemsetAsync(spec, 0, (size_t)BB * LN * 2 * sizeof(float), stream);
        fft_fused_kernel<<<BB * (HE / 4), 256, 0, stream>>>(q, k, spec);
        icorr_topk_kernel<<<BB, 256, 0, stream>>>(spec, wts, tao);
        const int n4 = BB * LN * HE / 4;
        gather_kernel<<<n4 / 256, 256, 0, stream>>>(v, wts, tao, out);
    }
}

// Round 16
// 161.825 us; speedup vs baseline: 1.6176x; 1.6176x over previous
//
#include <hip/hip_runtime.h>
#include <math.h>

#define LN      2048
#define LOG2L   11
#define BB      16
#define HE      512            // H*E channels
#define KTOP    7              // int(log(2048)) = 7
#define TWO_PI  6.283185307179586f
#define RC      0.70710678118654752f

// XOR swizzle on element index for LDS FFT buffers.
#define SIG(e)  ((e) ^ (((e) >> 5) & 31))

struct c32 { float x, y; };
__device__ __forceinline__ c32 cmul(c32 a, c32 b) {
    return { a.x * b.x - a.y * b.y, a.x * b.y + a.y * b.x };
}
__device__ __forceinline__ c32 cadd(c32 a, c32 b) { return { a.x + b.x, a.y + b.y }; }
__device__ __forceinline__ c32 csub(c32 a, c32 b) { return { a.x - b.x, a.y - b.y }; }

// fp32 -> bf16 (RNE) and packed helpers for the staged z buffer.
__device__ __forceinline__ unsigned short f2bf(float f) {
    unsigned u = __float_as_uint(f);
    u = (u + 0x7FFFu + ((u >> 16) & 1u)) >> 16;
    return (unsigned short)u;
}
__device__ __forceinline__ unsigned pkz(float re, float im) {
    return (unsigned)f2bf(re) | ((unsigned)f2bf(im) << 16);
}

__device__ __forceinline__ void dft4(c32 a, c32 b, c32 c, c32 d,
                                     c32& y0, c32& y1, c32& y2, c32& y3) {
    c32 t0 = cadd(a, c), t1 = csub(a, c);
    c32 t2 = cadd(b, d);
    c32 t3 = { b.y - d.y, d.x - b.x };          // -i*(b-d)
    y0 = cadd(t0, t2);
    y1 = cadd(t1, t3);
    y2 = csub(t0, t2);
    y3 = csub(t1, t3);
}

__device__ __forceinline__ void dft8(const c32* x, c32* y) {
    c32 e0, e1, e2, e3, o0, o1, o2, o3;
    dft4(x[0], x[2], x[4], x[6], e0, e1, e2, e3);
    dft4(x[1], x[3], x[5], x[7], o0, o1, o2, o3);
    c32 p1 = { RC * (o1.x + o1.y), RC * (o1.y - o1.x) };
    c32 p2 = { o2.y, -o2.x };
    c32 p3 = { RC * (o3.y - o3.x), -RC * (o3.x + o3.y) };
    y[0] = cadd(e0, o0); y[4] = csub(e0, o0);
    y[1] = cadd(e1, p1); y[5] = csub(e1, p1);
    y[2] = cadd(e2, p2); y[6] = csub(e2, p2);
    y[3] = cadd(e3, p3); y[7] = csub(e3, p3);
}

// Twiddle set for one stage: W[k-1] = W_2048^{pm*k}, k=1..7 (tree, depth<=2).
__device__ __forceinline__ void mk_tw(int pm, c32* W) {
    float sn, cs;
    __sincosf(-(TWO_PI / (float)LN) * (float)pm, &sn, &cs);
    const c32 w1 = { cs, sn };
    const c32 w2 = cmul(w1, w1);
    const c32 w3 = cmul(w1, w2);
    const c32 w4 = cmul(w2, w2);
    W[0] = w1; W[1] = w2; W[2] = w3; W[3] = w4;
    W[4] = cmul(w1, w4); W[5] = cmul(w2, w4); W[6] = cmul(w3, w4);
}

// Whole-WG Stockham DIF radix-8 stage from LDS, twiddles pre-hoisted.
template<int LOG2M>
__device__ __forceinline__ void r8_ld(float2* Z, int tid, const c32* TW) {
    c32 v[8];
    #pragma unroll
    for (int r = 0; r < 8; ++r) {
        float2 z = Z[SIG(tid + (r << 8))];
        v[r] = { z.x, z.y };
    }
    c32 y[8];
    dft8(v, y);
    #pragma unroll
    for (int kk = 1; kk < 8; ++kk) y[kk] = cmul(y[kk], TW[kk - 1]);
    __syncthreads();
    const int q_ = tid & ((1 << LOG2M) - 1);
    const int ob = q_ + ((tid - q_) << 3);       // q + 8*m*p
    #pragma unroll
    for (int kk = 0; kk < 8; ++kk)
        Z[SIG(ob + (kk << LOG2M))] = make_float2(y[kk].x, y[kk].y);
    __syncthreads();
}

// Final radix-4 stage, m=512 (twiddle-free), 512 butterflies / 256 threads.
__device__ __forceinline__ void r4_final_wg(float2* Z, int tid) {
    c32 v[2][4];
    #pragma unroll
    for (int u = 0; u < 2; ++u) {
        const int j = tid + (u << 8);
        #pragma unroll
        for (int r = 0; r < 4; ++r) {
            float2 z = Z[SIG(j + (r << 9))];
            v[u][r] = { z.x, z.y };
        }
    }
    __syncthreads();
    #pragma unroll
    for (int u = 0; u < 2; ++u) {
        const int j = tid + (u << 8);
        c32 y0, y1, y2, y3;
        dft4(v[u][0], v[u][1], v[u][2], v[u][3], y0, y1, y2, y3);
        Z[SIG(j)]        = make_float2(y0.x, y0.y);
        Z[SIG(j + 512)]  = make_float2(y1.x, y1.y);
        Z[SIG(j + 1024)] = make_float2(y2.x, y2.y);
        Z[SIG(j + 1536)] = make_float2(y3.x, y3.y);
    }
    __syncthreads();
}

// ---------------------------------------------------------------------------
// Kernel T v4: coalesced transpose, float4 global loads, writes PACKED
// z = (bf16(q), bf16(k)) as one uint per complex into [b][c][l] (64 MB, ws).
// Write bytes HALVED vs fp32 staging.
// ---------------------------------------------------------------------------
__global__ __launch_bounds__(256) void transpose_pack_kernel(
    const float* __restrict__ q, const float* __restrict__ k,
    unsigned* __restrict__ z) {
    __shared__ float2 tile[64][65];
    const int tid = threadIdx.x;
    const int bid = blockIdx.x;
    const int b  = bid >> 8;
    const int lt = (bid >> 3) & 31;
    const int ct = bid & 7;
    const int l0 = lt << 6, c0 = ct << 6;
    const int g16 = tid >> 4;               // 0..15
    const int m16 = (tid & 15) << 2;        // 0,4,..,60
    #pragma unroll
    for (int ii = 0; ii < 4; ++ii) {
        const int r = g16 + (ii << 4);      // l offset 0..63
        const size_t src = ((size_t)(b * LN + l0 + r)) * HE + c0 + m16;
        const float4 qv = *(const float4*)(q + src);
        const float4 kv = *(const float4*)(k + src);
        tile[r][m16 + 0] = make_float2(qv.x, kv.x);
        tile[r][m16 + 1] = make_float2(qv.y, kv.y);
        tile[r][m16 + 2] = make_float2(qv.z, kv.z);
        tile[r][m16 + 3] = make_float2(qv.w, kv.w);
    }
    __syncthreads();
    #pragma unroll
    for (int ii = 0; ii < 4; ++ii) {
        const int rc = g16 + (ii << 4);     // c offset 0..63
        const float2 t0 = tile[m16 + 0][rc];
        const float2 t1 = tile[m16 + 1][rc];
        const float2 t2 = tile[m16 + 2][rc];
        const float2 t3 = tile[m16 + 3][rc];
        unsigned* dst = z + ((size_t)(b * HE + c0 + rc)) * LN + l0 + m16;
        uint4 w;
        w.x = pkz(t0.x, t0.y);
        w.y = pkz(t1.x, t1.y);
        w.z = pkz(t2.x, t2.y);
        w.w = pkz(t3.x, t3.y);
        *(uint4*)dst = w;
    }
}

// ---------------------------------------------------------------------------
// Kernel A: r13-exact FFT structure (stage-0 from global in registers,
// hoisted twiddle trees, Hermitian-half flush, b = wg>>7 L2 locality),
// fed from bf16-packed z (1 dword per complex -> fetch bytes halved).
// ---------------------------------------------------------------------------
__global__ __launch_bounds__(256) void fft_reg0_kernel(
    const unsigned* __restrict__ z,
    float* __restrict__ spec /* [BB][LN][2], only f<=1024 written */) {
    __shared__ float2 Z[LN];                     // 16 KB
    const int tid = threadIdx.x;
    const int wg  = blockIdx.x;                  // 2048
    const int b   = wg >> 7;                     // L2-locality mapping
    const int c0  = (wg & 127) << 2;

    c32 TW0[7], TW1[7], TW2[7];                  // channel-invariant
    mk_tw(tid, TW0);
    mk_tw(tid & ~7, TW1);
    mk_tw(tid & ~63, TW2);

    float accx[4], accy[4];
    #pragma unroll
    for (int i = 0; i < 4; ++i) { accx[i] = 0.f; accy[i] = 0.f; }
    float a1024 = 0.f;

    #pragma unroll 1
    for (int ch = 0; ch < 4; ++ch) {
        const unsigned* zc = z + (((size_t)(b * HE + c0 + ch)) << LOG2L);
        // stage 0 straight from global: 1 dword per complex, coalesced
        c32 v[8];
        #pragma unroll
        for (int r = 0; r < 8; ++r) {
            const unsigned u = zc[tid + (r << 8)];
            v[r].x = __uint_as_float(u << 16);
            v[r].y = __uint_as_float(u & 0xFFFF0000u);
        }
        c32 y[8];
        dft8(v, y);
        #pragma unroll
        for (int kk = 1; kk < 8; ++kk) y[kk] = cmul(y[kk], TW0[kk - 1]);
        __syncthreads();                         // Z free (prev unpack done)
        #pragma unroll
        for (int kk = 0; kk < 8; ++kk)           // ob = 8*tid, contiguous
            Z[SIG((tid << 3) + kk)] = make_float2(y[kk].x, y[kk].y);
        __syncthreads();

        r8_ld<3>(Z, tid, TW1);
        r8_ld<6>(Z, tid, TW2);
        r4_final_wg(Z, tid);

        // Hermitian-half unpack: S = Q*conj(K), f in [0,1024)
        #pragma unroll
        for (int i = 0; i < 4; ++i) {
            const int f = tid + (i << 8);
            const int g = (LN - f) & (LN - 1);
            const float2 zf = Z[SIG(f)];
            const float2 zm = Z[SIG(g)];
            const float Qr = 0.5f * (zf.x + zm.x);
            const float Qi = 0.5f * (zf.y - zm.y);
            const float Kr = 0.5f * (zf.y + zm.y);
            const float Ki = -0.5f * (zf.x - zm.x);
            accx[i] += Qr * Kr + Qi * Ki;
            accy[i] += Qi * Kr - Qr * Ki;
        }
        if (tid == 0) {                          // f = 1024: S real
            const float2 zf = Z[SIG(1024)];
            a1024 += zf.x * zf.y;
        }
    }
    #pragma unroll
    for (int i = 0; i < 4; ++i) {
        const int f = tid + (i << 8);
        atomicAdd(&spec[((size_t)b * LN + f) * 2 + 0], accx[i]);
        atomicAdd(&spec[((size_t)b * LN + f) * 2 + 1], accy[i]);
    }
    if (tid == 0)
        atomicAdd(&spec[((size_t)b * LN + 1024) * 2 + 0], a1024);
}

// ---------------------------------------------------------------------------
// Fallback (raw layout, round-3 path; flush gated to f<=1024) — only if ws
// is too small for the packed staging buffer.
// ---------------------------------------------------------------------------
template<int LOG2M>
__device__ __forceinline__ void r8_stage(float2* Z, int lane) {
    c32 v[32];
    #pragma unroll
    for (int u = 0; u < 4; ++u) {
        const int j = lane + (u << 6);
        #pragma unroll
        for (int r = 0; r < 8; ++r) {
            float2 z = Z[SIG(j + (r << 8))];
            v[(u << 3) + r] = { z.x, z.y };
        }
    }
    c32 y[32];
    #pragma unroll
    for (int u = 0; u < 4; ++u) {
        const int j  = lane + (u << 6);
        const int pm = j & ~((1 << LOG2M) - 1);
        dft8(&v[u << 3], &y[u << 3]);
        float sn, cs;
        __sincosf(-(TWO_PI / (float)LN) * (float)pm, &sn, &cs);
        c32 base = { cs, sn };
        c32 t = base;
        #pragma unroll
        for (int kk = 1; kk < 8; ++kk) {
            y[(u << 3) + kk] = cmul(y[(u << 3) + kk], t);
            if (kk < 7) t = cmul(t, base);
        }
    }
    __syncthreads();
    #pragma unroll
    for (int u = 0; u < 4; ++u) {
        const int j  = lane + (u << 6);
        const int q_ = j & ((1 << LOG2M) - 1);
        const int ob = q_ + ((j - q_) << 3);
        #pragma unroll
        for (int kk = 0; kk < 8; ++kk) {
            c32 yy = y[(u << 3) + kk];
            Z[SIG(ob + (kk << LOG2M))] = make_float2(yy.x, yy.y);
        }
    }
    __syncthreads();
}

__device__ __forceinline__ void r4_final(float2* Z, int lane) {
    c32 v[32];
    #pragma unroll
    for (int u = 0; u < 8; ++u) {
        const int j = lane + (u << 6);
        #pragma unroll
        for (int r = 0; r < 4; ++r) {
            float2 z = Z[SIG(j + (r << 9))];
            v[(u << 2) + r] = { z.x, z.y };
        }
    }
    __syncthreads();
    #pragma unroll
    for (int u = 0; u < 8; ++u) {
        const int j = lane + (u << 6);
        c32 y0, y1, y2, y3;
        dft4(v[u << 2], v[(u << 2) + 1], v[(u << 2) + 2], v[(u << 2) + 3],
             y0, y1, y2, y3);
        Z[SIG(j)]        = make_float2(y0.x, y0.y);
        Z[SIG(j + 512)]  = make_float2(y1.x, y1.y);
        Z[SIG(j + 1024)] = make_float2(y2.x, y2.y);
        Z[SIG(j + 1536)] = make_float2(y3.x, y3.y);
    }
    __syncthreads();
}

__global__ __launch_bounds__(256) void fft_fused_kernel(
    const float* __restrict__ qg, const float* __restrict__ kg,
    float* __restrict__ spec) {
    __shared__ float2 zb[4][LN];
    const int t    = threadIdx.x;
    const int bid  = blockIdx.x;
    const int wgid = ((bid & 7) << 8) | (bid >> 3);
    const int b    = wgid >> 7;
    const int c0   = (wgid & 127) << 2;
    #pragma unroll
    for (int i = 0; i < 8; ++i) {
        const int l = t + (i << 8);
        const size_t base = (size_t)(b * LN + l) * HE + c0;
        const float4 qv = *(const float4*)(qg + base);
        const float4 kv = *(const float4*)(kg + base);
        const int sl = SIG(l);
        zb[0][sl] = make_float2(qv.x, kv.x);
        zb[1][sl] = make_float2(qv.y, kv.y);
        zb[2][sl] = make_float2(qv.z, kv.z);
        zb[3][sl] = make_float2(qv.w, kv.w);
    }
    __syncthreads();
    const int w    = t >> 6;
    const int lane = t & 63;
    float2* Z = zb[w];
    r8_stage<0>(Z, lane);
    r8_stage<3>(Z, lane);
    r8_stage<6>(Z, lane);
    r4_final(Z, lane);
    float sx[32], sy[32];
    #pragma unroll
    for (int i = 0; i < 32; ++i) {
        const int f = lane + (i << 6);
        const float2 zf = Z[SIG(f)];
        const float2 zm = Z[SIG((LN - f) & (LN - 1))];
        const float Qr = 0.5f * (zf.x + zm.x);
        const float Qi = 0.5f * (zf.y - zm.y);
        const float Kr = 0.5f * (zf.y + zm.y);
        const float Ki = -0.5f * (zf.x - zm.x);
        sx[i] = Qr * Kr + Qi * Ki;
        sy[i] = Qi * Kr - Qr * Ki;
    }
    __syncthreads();
    #pragma unroll
    for (int i = 0; i < 32; ++i) {
        const int f = lane + (i << 6);
        Z[SIG(f)] = make_float2(sx[i], sy[i]);
    }
    __syncthreads();
    #pragma unroll
    for (int i = 0; i < 8; ++i) {
        const int f  = t + (i << 8);
        if (f <= 1024) {
            const int sf = SIG(f);
            const float rx = zb[0][sf].x + zb[1][sf].x + zb[2][sf].x + zb[3][sf].x;
            const float ry = zb[0][sf].y + zb[1][sf].y + zb[2][sf].y + zb[3][sf].y;
            atomicAdd(&spec[((size_t)b * LN + f) * 2 + 0], rx);
            atomicAdd(&spec[((size_t)b * LN + f) * 2 + 1], ry);
        }
    }
}

// ---------------------------------------------------------------------------
// Kernel B: per-b inverse transform -> mean corr, top-7 + softmax.
// Spectrum stored Hermitian-half: reflect for f > 1024.
// ---------------------------------------------------------------------------
__device__ __forceinline__ unsigned bitrev11(unsigned x) {
    return __brev(x) >> (32 - LOG2L);
}

__global__ __launch_bounds__(256) void icorr_topk_kernel(
    const float* __restrict__ spec, float* __restrict__ wts, int* __restrict__ tao) {
    __shared__ float2 zbuf[LN];
    __shared__ float2 tw[LN / 2];
    __shared__ float  cr[LN];
    __shared__ float  rv[256];
    __shared__ int    ri[256];
    __shared__ float  topv[KTOP];
    __shared__ int    topi[KTOP];
    const int tid = threadIdx.x;
    const int b   = blockIdx.x;
    for (int p = tid; p < LN / 2; p += 256) {
        float s, c;
        sincosf(-TWO_PI * (float)p / (float)LN, &s, &c);
        tw[p] = make_float2(c, s);
    }
    for (int f = tid; f < LN; f += 256) {
        const int  fs  = (f <= 1024) ? f : (LN - f);
        const float sg = (f <= 1024) ? -1.f : 1.f;   // zbuf = conj(S[f])
        float sr = spec[((size_t)b * LN + fs) * 2 + 0];
        float si = spec[((size_t)b * LN + fs) * 2 + 1];
        zbuf[bitrev11((unsigned)f)] = make_float2(sr, sg * si);
    }
    __syncthreads();
    for (int s = 0; s < LOG2L; ++s) {
        const int half = 1 << s;
        for (int j = tid; j < LN / 2; j += 256) {
            const int grp = j >> s;
            const int pos = j & (half - 1);
            const int i0  = (grp << (s + 1)) + pos;
            const int i1  = i0 + half;
            const float2 w = tw[pos << (LOG2L - 1 - s)];
            float2 a  = zbuf[i0];
            float2 bv = zbuf[i1];
            float tr = w.x * bv.x - w.y * bv.y;
            float ti = w.x * bv.y + w.y * bv.x;
            zbuf[i0] = make_float2(a.x + tr, a.y + ti);
            zbuf[i1] = make_float2(a.x - tr, a.y - ti);
        }
        __syncthreads();
    }
    const float scale = 1.0f / ((float)LN * (float)HE);
    for (int t = tid; t < LN; t += 256) cr[t] = zbuf[t].x * scale;
    __syncthreads();
    for (int it = 0; it < KTOP; ++it) {
        float mv = -INFINITY;
        int   mi = 0;
        for (int t = tid; t < LN; t += 256) {
            float v = cr[t];
            if (v > mv) { mv = v; mi = t; }
        }
        rv[tid] = mv; ri[tid] = mi;
        __syncthreads();
        for (int off = 128; off > 0; off >>= 1) {
            if (tid < off) {
                float ov = rv[tid + off]; int oi = ri[tid + off];
                if (ov > rv[tid] || (ov == rv[tid] && oi < ri[tid])) {
                    rv[tid] = ov; ri[tid] = oi;
                }
            }
            __syncthreads();
        }
        if (tid == 0) {
            topv[it] = rv[0];
            topi[it] = ri[0];
            cr[ri[0]] = -INFINITY;
        }
        __syncthreads();
    }
    if (tid == 0) {
        float m = topv[0];
        float s = 0.f;
        float ex[KTOP];
        for (int j = 0; j < KTOP; ++j) { ex[j] = __expf(topv[j] - m); s += ex[j]; }
        float inv = 1.0f / s;
        for (int j = 0; j < KTOP; ++j) {
            wts[b * 8 + j] = ex[j] * inv;
            tao[b * 8 + j] = topi[j];
        }
    }
}

// ---------------------------------------------------------------------------
// Kernel C: out[b,l,:,:] = sum_j w[b,j] * V[b,(l+tao_j)%L,:,:]
// ---------------------------------------------------------------------------
__global__ __launch_bounds__(256) void gather_kernel(
    const float* __restrict__ v, const float* __restrict__ wts,
    const int* __restrict__ tao, float* __restrict__ out) {
    __shared__ float lw[KTOP];
    __shared__ int   lt[KTOP];
    const int tid = threadIdx.x;
    const int bid = blockIdx.x;
    const int wg  = ((bid & 7) << 11) | (bid >> 3);
    const long long idx = (long long)wg * 256 + tid;
    const int c4 = (int)(idx & 127);
    const int l  = (int)((idx >> 7) & (LN - 1));
    const int b  = (int)(idx >> 18);
    if (tid < KTOP) {
        lw[tid] = wts[b * 8 + tid];
        lt[tid] = tao[b * 8 + tid];
    }
    __syncthreads();
    const float4* v4 = (const float4*)v;
    float4 a = make_float4(0.f, 0.f, 0.f, 0.f);
    #pragma unroll
    for (int j = 0; j < KTOP; ++j) {
        int ls = (l + lt[j]) & (LN - 1);
        float4 x = v4[((size_t)b * LN + ls) * 128 + c4];
        float w = lw[j];
        a.x += w * x.x; a.y += w * x.y; a.z += w * x.z; a.w += w * x.w;
    }
    ((float4*)out)[idx] = a;
}

// ---------------------------------------------------------------------------
extern "C" void kernel_launch(void* const* d_in, const int* in_sizes, int n_in,
                              void* d_out, int out_size, void* d_ws, size_t ws_size,
                              hipStream_t stream) {
    const float* q = (const float*)d_in[0];
    const float* k = (const float*)d_in[1];
    const float* v = (const float*)d_in[2];
    float* out = (float*)d_out;

    const size_t nC   = (size_t)BB * HE * LN;          // complex count, 16.7M
    const size_t need = nC * 4 + (size_t)BB * LN * 2 * 4 + (size_t)BB * 8 * 8;

    if (ws_size >= need) {
        unsigned* z    = (unsigned*)d_ws;              // bf16-packed z: 64 MB
        float*    spec = (float*)(z + nC);
        float*    wts  = spec + (size_t)BB * LN * 2;
        int*      tao  = (int*)(wts + BB * 8);

        hipMemsetAsync(spec, 0, (size_t)BB * LN * 2 * sizeof(float), stream);
        transpose_pack_kernel<<<BB * 32 * 8, 256, 0, stream>>>(q, k, z);
        fft_reg0_kernel<<<BB * (HE / 4), 256, 0, stream>>>(z, spec);
        icorr_topk_kernel<<<BB, 256, 0, stream>>>(spec, wts, tao);
        const int n4 = BB * LN * HE / 4;
        gather_kernel<<<n4 / 256, 256, 0, stream>>>(v, wts, tao, out);
    } else {
        float* spec = (float*)d_ws;
        float* wts  = spec + (size_t)BB * LN * 2;
        int*   tao  = (int*)(wts + BB * 8);
        hipMemsetAsync(spec, 0, (size_t)BB * LN * 2 * sizeof(float), stream);
        fft_fused_kernel<<<BB * (HE / 4), 256, 0, stream>>>(q, k, spec);
        icorr_topk_kernel<<<BB, 256, 0, stream>>>(spec, wts, tao);
        const int n4 = BB * LN * HE / 4;
        gather_kernel<<<n4 / 256, 256, 0, stream>>>(v, wts, tao, out);
    }
}